// Round 1
// baseline (75.484 us; speedup 1.0000x reference)
//
#include <hip/hip_runtime.h>
#include <math.h>

constexpr int B = 16384;
constexpr int V = 8;
constexpr int J = 21;

__global__ __launch_bounds__(256)
void triangulate_kernel(const float* __restrict__ intr,   // (B,V,3,3)
                        const float* __restrict__ extr,   // (B,V,3,4)
                        const float* __restrict__ uv,     // (B,V,J,2)
                        const float* __restrict__ conf,   // (B,V,J)
                        float* __restrict__ out)          // (B,J,3)
{
    int t = blockIdx.x * blockDim.x + threadIdx.x;
    if (t >= B * J) return;
    int b = t / J;
    int j = t - b * J;

    // ---- accumulate M = A^T A (4x4 symmetric, upper triangle) in fp64 ----
    double m00 = 0, m01 = 0, m02 = 0, m03 = 0;
    double m11 = 0, m12 = 0, m13 = 0;
    double m22 = 0, m23 = 0;
    double m33 = 0;
    float total_w = 0.0f;

    for (int v = 0; v < V; ++v) {
        const float* Kp = intr + (size_t)(b * V + v) * 9;
        const float* Ep = extr + (size_t)(b * V + v) * 12;
        float K0 = Kp[0], K1 = Kp[1], K2 = Kp[2];
        float K3 = Kp[3], K4 = Kp[4], K5 = Kp[5];
        float K6 = Kp[6], K7 = Kp[7], K8 = Kp[8];

        float P0[4], P1[4], P2[4];
        #pragma unroll
        for (int k = 0; k < 4; ++k) {
            float e0 = Ep[k], e1 = Ep[4 + k], e2 = Ep[8 + k];
            P0[k] = K0 * e0 + K1 * e1 + K2 * e2;
            P1[k] = K3 * e0 + K4 * e1 + K5 * e2;
            P2[k] = K6 * e0 + K7 * e1 + K8 * e2;
        }

        size_t uvbase = (size_t)(b * V + v) * J + j;
        float uu = uv[uvbase * 2 + 0];
        float vv = uv[uvbase * 2 + 1];
        float w  = conf[uvbase];
        total_w += w;

        // rows in fp32, matching reference rounding of A
        float r0[4], r1[4];
        #pragma unroll
        for (int k = 0; k < 4; ++k) {
            r0[k] = w * (uu * P2[k] - P0[k]);
            r1[k] = w * (vv * P2[k] - P1[k]);
        }

        m00 += (double)r0[0] * r0[0] + (double)r1[0] * r1[0];
        m01 += (double)r0[0] * r0[1] + (double)r1[0] * r1[1];
        m02 += (double)r0[0] * r0[2] + (double)r1[0] * r1[2];
        m03 += (double)r0[0] * r0[3] + (double)r1[0] * r1[3];
        m11 += (double)r0[1] * r0[1] + (double)r1[1] * r1[1];
        m12 += (double)r0[1] * r0[2] + (double)r1[1] * r1[2];
        m13 += (double)r0[1] * r0[3] + (double)r1[1] * r1[3];
        m22 += (double)r0[2] * r0[2] + (double)r1[2] * r1[2];
        m23 += (double)r0[2] * r0[3] + (double)r1[2] * r1[3];
        m33 += (double)r0[3] * r0[3] + (double)r1[3] * r1[3];
    }

    // ---- cyclic Jacobi eigensolver on 4x4 symmetric M (fp64) ----
    double m[4][4] = {{m00, m01, m02, m03},
                      {m01, m11, m12, m13},
                      {m02, m12, m22, m23},
                      {m03, m13, m23, m33}};
    double Vv[4][4];
    #pragma unroll
    for (int i = 0; i < 4; ++i)
        #pragma unroll
        for (int k = 0; k < 4; ++k)
            Vv[i][k] = (i == k) ? 1.0 : 0.0;

    const int PP[6] = {0, 0, 0, 1, 1, 2};
    const int QQ[6] = {1, 2, 3, 2, 3, 3};

    for (int sweep = 0; sweep < 8; ++sweep) {
        #pragma unroll
        for (int pi = 0; pi < 6; ++pi) {
            const int p = PP[pi], q = QQ[pi];
            double apq = m[p][q];
            if (apq != 0.0) {
                double app = m[p][p], aqq = m[q][q];
                double tau = (aqq - app) / (2.0 * apq);
                double tt  = (tau >= 0.0 ? 1.0 : -1.0) /
                             (fabs(tau) + sqrt(1.0 + tau * tau));
                double c = 1.0 / sqrt(1.0 + tt * tt);
                double s = tt * c;
                m[p][p] = app - tt * apq;
                m[q][q] = aqq + tt * apq;
                m[p][q] = 0.0;
                m[q][p] = 0.0;
                #pragma unroll
                for (int r = 0; r < 4; ++r) {
                    if (r != p && r != q) {
                        double arp = m[r][p], arq = m[r][q];
                        double np_ = c * arp - s * arq;
                        double nq_ = s * arp + c * arq;
                        m[r][p] = np_; m[p][r] = np_;
                        m[r][q] = nq_; m[q][r] = nq_;
                    }
                }
                #pragma unroll
                for (int r = 0; r < 4; ++r) {
                    double vrp = Vv[r][p], vrq = Vv[r][q];
                    Vv[r][p] = c * vrp - s * vrq;
                    Vv[r][q] = s * vrp + c * vrq;
                }
            }
        }
    }

    // ---- pick eigenvector of smallest eigenvalue (no runtime array index) ----
    double ev0 = m[0][0], ev1 = m[1][1], ev2 = m[2][2], ev3 = m[3][3];
    int k = 0;
    double best = ev0;
    if (ev1 < best) { best = ev1; k = 1; }
    if (ev2 < best) { best = ev2; k = 2; }
    if (ev3 < best) { best = ev3; k = 3; }

    double x0 = (k == 0) ? Vv[0][0] : (k == 1) ? Vv[0][1] : (k == 2) ? Vv[0][2] : Vv[0][3];
    double x1 = (k == 0) ? Vv[1][0] : (k == 1) ? Vv[1][1] : (k == 2) ? Vv[1][2] : Vv[1][3];
    double x2 = (k == 0) ? Vv[2][0] : (k == 1) ? Vv[2][1] : (k == 2) ? Vv[2][2] : Vv[2][3];
    double x3 = (k == 0) ? Vv[3][0] : (k == 1) ? Vv[3][1] : (k == 2) ? Vv[3][2] : Vv[3][3];

    // ---- dehomogenize in fp32, matching reference semantics ----
    float xw = (float)x3;
    bool valid = (total_w > 0.1f) && (fabsf(xw) > 1e-6f);
    float denom = xw + 1e-8f;
    float o0 = valid ? (float)x0 / denom : 0.0f;
    float o1 = valid ? (float)x1 / denom : 0.0f;
    float o2 = valid ? (float)x2 / denom : 0.0f;

    out[(size_t)t * 3 + 0] = o0;
    out[(size_t)t * 3 + 1] = o1;
    out[(size_t)t * 3 + 2] = o2;
}

extern "C" void kernel_launch(void* const* d_in, const int* in_sizes, int n_in,
                              void* d_out, int out_size, void* d_ws, size_t ws_size,
                              hipStream_t stream) {
    const float* intr = (const float*)d_in[0];
    const float* extr = (const float*)d_in[1];
    const float* uv   = (const float*)d_in[2];
    const float* conf = (const float*)d_in[3];
    float* out = (float*)d_out;

    int total = B * J;                 // 344064
    int block = 256;
    int grid = (total + block - 1) / block;   // 1344
    triangulate_kernel<<<grid, block, 0, stream>>>(intr, extr, uv, conf, out);
}